// Round 12
// baseline (135.037 us; speedup 1.0000x reference)
//
#include <hip/hip_runtime.h>

typedef __attribute__((ext_vector_type(4))) float f32x4;
typedef __attribute__((ext_vector_type(8))) short bf16x8;

// f32 -> bf16 round-to-nearest-even
__device__ inline unsigned short f2bf(float x) {
  unsigned u = __builtin_bit_cast(unsigned, x);
  u += 0x7fffu + ((u >> 16) & 1u);
  return (unsigned short)(u >> 16);
}

__device__ inline bf16x8 pack8(f32x4 lo, f32x4 hi) {
  bf16x8 r;
  r[0] = (short)f2bf(lo[0]); r[1] = (short)f2bf(lo[1]);
  r[2] = (short)f2bf(lo[2]); r[3] = (short)f2bf(lo[3]);
  r[4] = (short)f2bf(hi[0]); r[5] = (short)f2bf(hi[1]);
  r[6] = (short)f2bf(hi[2]); r[7] = (short)f2bf(hi[3]);
  return r;
}

__device__ inline bf16x8 cvt8(const float* __restrict__ p) {
  return pack8(*(const f32x4*)p, *(const f32x4*)(p + 4));
}

// Device-scope grid barrier. bar = {count, generation}, pre-zeroed per call.
// All 256 blocks are co-resident (grid == CU count), so arrival is guaranteed;
// bounded spin avoids a hang if that ever breaks.
__device__ __forceinline__ void grid_barrier(unsigned* bar, unsigned nblk) {
  __syncthreads();
  if (threadIdx.x == 0) {
    __threadfence();  // release: make this block's global writes visible
    unsigned gen = __hip_atomic_load(bar + 1, __ATOMIC_RELAXED,
                                     __HIP_MEMORY_SCOPE_AGENT);
    unsigned arrived = __hip_atomic_fetch_add(bar, 1u, __ATOMIC_ACQ_REL,
                                              __HIP_MEMORY_SCOPE_AGENT);
    if (arrived == nblk - 1u) {
      __hip_atomic_store(bar, 0u, __ATOMIC_RELAXED, __HIP_MEMORY_SCOPE_AGENT);
      __hip_atomic_fetch_add(bar + 1, 1u, __ATOMIC_RELEASE,
                             __HIP_MEMORY_SCOPE_AGENT);
    } else {
      int t = 0;
      while (__hip_atomic_load(bar + 1, __ATOMIC_ACQUIRE,
                               __HIP_MEMORY_SCOPE_AGENT) == gen) {
        __builtin_amdgcn_s_sleep(8);
        if (++t > (1 << 20)) break;  // hang-safety valve
      }
    }
    __threadfence();  // acquire side
  }
  __syncthreads();
}

// mega: phase1 = gemm1 (e=X@Wr^T+br -> bf16) + cvec zero; barrier;
//       phase2 = gemm2 (UVt=[W1r;W1c]@e^T (+b1), fused cvec); barrier;
//       phase3 = pairwise over 1056 tile-pair tasks (persistent loop).
__global__ __launch_bounds__(256) void mega_kernel(
    const float* __restrict__ X, const float* __restrict__ Wr,
    const float* __restrict__ br, const float* __restrict__ W1,
    const float* __restrict__ b1, const float* __restrict__ W2,
    const float* __restrict__ b2p, unsigned short* __restrict__ Ebf,
    float* __restrict__ UVt, float* __restrict__ cvec,
    unsigned* __restrict__ bar, float* __restrict__ Out) {
  __shared__ float u_s[4][64][36];
  __shared__ float v_s[4][64][36];
  __shared__ float w2_s[256];
  __shared__ float cuv[64];

  int tid = threadIdx.x, wave = tid >> 6, lane = tid & 63;
  int lr = lane & 15, kg = (lane >> 4) * 8;
  int rb = (lane >> 4) * 4;

  // ---------- phase 1: gemm1 (R11 body; 1024 wave-tasks) ----------
  if (tid < 16) cvec[blockIdx.x * 16 + tid] = 0.f;  // 256*16 = 4096
  {
    int w = blockIdx.x * 4 + wave;
    int tok0 = (w >> 3) * 16, n0 = (w & 7) * 16;
    const float* ap = X + (size_t)(tok0 + lr) * 768 + kg;
    const float* bp = Wr + (size_t)(n0 + lr) * 768 + kg;
    f32x4 acc = {0, 0, 0, 0};
#pragma unroll 4
    for (int k0 = 0; k0 < 768; k0 += 32) {
      bf16x8 a = cvt8(ap + k0);
      bf16x8 b = cvt8(bp + k0);
      acc = __builtin_amdgcn_mfma_f32_16x16x32_bf16(a, b, acc, 0, 0, 0);
    }
    float bias = br[n0 + lr];
#pragma unroll
    for (int r = 0; r < 4; ++r)
      Ebf[(size_t)(tok0 + rb + r) * 128 + n0 + lr] = f2bf(acc[r] + bias);
  }
  grid_barrier(bar, 256);

  // ---------- phase 2: gemm2 + fused cvec (R11 body; 1024 wave-tasks) ----------
  {
    int w = blockIdx.x * 4 + wave;
    int t0 = (w >> 5) * 64;
    int m0 = (w & 31) * 16;
    const float* aB = (m0 < 256)
        ? (W1 + (size_t)(m0 + lr) * 256 + kg)
        : (W1 + (size_t)(m0 - 256 + lr) * 256 + 128 + kg);
    f32x4 acc[4] = {{0,0,0,0},{0,0,0,0},{0,0,0,0},{0,0,0,0}};
#pragma unroll
    for (int k0 = 0; k0 < 128; k0 += 32) {
      bf16x8 a = cvt8(aB + k0);
#pragma unroll
      for (int t = 0; t < 4; ++t) {
        bf16x8 b = *(const bf16x8*)(Ebf + (size_t)(t0 + t * 16 + lr) * 128 + kg + k0);
        acc[t] = __builtin_amdgcn_mfma_f32_16x16x32_bf16(a, b, acc[t], 0, 0, 0);
      }
    }
    float p[4] = {0.f, 0.f, 0.f, 0.f};
#pragma unroll
    for (int t = 0; t < 4; ++t) {
#pragma unroll
      for (int r = 0; r < 4; ++r) {
        int m = m0 + rb + r;
        float val = acc[t][r] + ((m0 < 256) ? b1[m] : 0.f);
        UVt[(size_t)m * 2048 + t0 + t * 16 + lr] = val;
        p[t] = fmaf(W2[m & 255], val, p[t]);
      }
    }
#pragma unroll
    for (int t = 0; t < 4; ++t) {
      p[t] += __shfl_xor(p[t], 16);
      p[t] += __shfl_xor(p[t], 32);
    }
    if (lane < 16) {
      int h = (m0 < 256) ? 0 : 1;
#pragma unroll
      for (int t = 0; t < 4; ++t)
        atomicAdd(&cvec[h * 2048 + t0 + t * 16 + lane], 0.5f * p[t]);
    }
  }
  grid_barrier(bar + 16, 256);

  // ---------- phase 3: pairwise (R11 body in a persistent task loop) ----------
  for (int task = blockIdx.x; task < 1056; task += 256) {
    __syncthreads();  // guard LDS reuse across iterations
    int b = task >= 528 ? 1 : 0;
    int p = task - b * 528;
    int it = 0;
    while (p >= 32 - it) { p -= 32 - it; ++it; }
    int jt = it + p;

    int utok = b * 1024 + it * 32;
    int vtok = b * 1024 + jt * 32;

    w2_s[tid] = W2[tid];
    if (tid < 32) cuv[tid] = cvec[utok + tid];
    else if (tid < 64) cuv[tid] = cvec[2048 + vtok + (tid - 32)];
    __syncthreads();

    int mr = lane >> 3, tq = (lane & 7) * 4;
    int tx = lane & 7, ty = lane >> 3;
    float acc[4][4] = {{0,0,0,0},{0,0,0,0},{0,0,0,0},{0,0,0,0}};

#pragma unroll
    for (int g = 0; g < 8; ++g) {
      int ml = g * 8 + mr;
      int m = wave * 64 + ml;
      *(f32x4*)&u_s[wave][ml][tq] = *(const f32x4*)(UVt + (size_t)m * 2048 + utok + tq);
      *(f32x4*)&v_s[wave][ml][tq] = *(const f32x4*)(UVt + (size_t)(256 + m) * 2048 + vtok + tq);
    }

    for (int ml = 0; ml < 64; ml += 4) {
      f32x4 wq = *(const f32x4*)&w2_s[wave * 64 + ml];
#pragma unroll
      for (int s = 0; s < 4; ++s) {
        f32x4 uu = *(const f32x4*)&u_s[wave][ml + s][4 * ty];
        f32x4 vv = *(const f32x4*)&v_s[wave][ml + s][4 * tx];
        float w = wq[s];
#pragma unroll
        for (int i = 0; i < 4; ++i)
#pragma unroll
          for (int j = 0; j < 4; ++j)
            acc[i][j] = fmaf(w, fabsf(uu[i] + vv[j]), acc[i][j]);
      }
    }

    float* ovp = (float*)u_s;   // [4][32][36] partials overlay
    float* t2p = (float*)v_s;   // [32][36] transposed tile overlay
    __syncthreads();
#pragma unroll
    for (int i = 0; i < 4; ++i) {
      f32x4 rv = {acc[i][0], acc[i][1], acc[i][2], acc[i][3]};
      *(f32x4*)&ovp[((size_t)wave * 32 + 4 * ty + i) * 36 + 4 * tx] = rv;
    }
    __syncthreads();

    int tc = lane & 7;
    int row = wave * 8 + (lane >> 3);
    float b2v = b2p[0];
    f32x4 sum = {0, 0, 0, 0};
#pragma unroll
    for (int q = 0; q < 4; ++q) {
      f32x4 part = *(const f32x4*)&ovp[((size_t)q * 32 + row) * 36 + 4 * tc];
#pragma unroll
      for (int j = 0; j < 4; ++j) sum[j] += part[j];
    }
    float cu = cuv[row];
    f32x4 val;
#pragma unroll
    for (int j = 0; j < 4; ++j)
      val[j] = 0.5f * sum[j] + cu + cuv[32 + 4 * tc + j] + b2v;

    *(f32x4*)&t2p[(size_t)row * 36 + 4 * tc] = val;

    size_t obase = (size_t)b << 20;
    int i0 = it * 32, j0 = jt * 32;
    if (it != jt)
      *(f32x4*)(Out + obase + (size_t)(i0 + row) * 1024 + j0 + 4 * tc) = val;
    else {
#pragma unroll
      for (int j = 0; j < 4; ++j) {
        int jl = 4 * tc + j;
        if (jl >= row) Out[obase + (size_t)(i0 + row) * 1024 + j0 + jl] = val[j];
      }
    }
    __syncthreads();
    f32x4 mv;
#pragma unroll
    for (int j = 0; j < 4; ++j) mv[j] = t2p[(size_t)(4 * tc + j) * 36 + row];
    if (it != jt)
      *(f32x4*)(Out + obase + (size_t)(j0 + row) * 1024 + i0 + 4 * tc) = mv;
    else {
#pragma unroll
      for (int j = 0; j < 4; ++j) {
        int c = 4 * tc + j;
        if (row > c) Out[obase + (size_t)(i0 + row) * 1024 + j0 + c] = mv[j];
      }
    }
  }
}

extern "C" void kernel_launch(void* const* d_in, const int* in_sizes, int n_in,
                              void* d_out, int out_size, void* d_ws, size_t ws_size,
                              hipStream_t stream) {
  (void)in_sizes; (void)n_in; (void)out_size; (void)ws_size;
  const float* X  = (const float*)d_in[0];
  const float* Wr = (const float*)d_in[1];
  const float* br = (const float*)d_in[2];
  const float* W1 = (const float*)d_in[3];
  const float* b1 = (const float*)d_in[4];
  const float* W2 = (const float*)d_in[5];
  const float* b2 = (const float*)d_in[6];
  float* Out = (float*)d_out;

  char* ws = (char*)d_ws;
  unsigned*       bar  = (unsigned*)(ws);                  //       128 B
  unsigned short* Ebf  = (unsigned short*)(ws + 128);      //   524,288 B
  float*          UVt  = (float*)(ws + 524416);            // 4,194,304 B
  float*          cvec = (float*)(ws + 4718720);           //    16,384 B

  hipMemsetAsync(bar, 0, 128, stream);
  mega_kernel<<<256, 256, 0, stream>>>(X, Wr, br, W1, b1, W2, b2, Ebf, UVt,
                                       cvec, bar, Out);
}

// Round 13
// 92.856 us; speedup vs baseline: 1.4543x; 1.4543x over previous
//
#include <hip/hip_runtime.h>

typedef __attribute__((ext_vector_type(4))) float f32x4;
typedef __attribute__((ext_vector_type(8))) short bf16x8;

// f32 -> bf16 round-to-nearest-even
__device__ inline unsigned short f2bf(float x) {
  unsigned u = __builtin_bit_cast(unsigned, x);
  u += 0x7fffu + ((u >> 16) & 1u);
  return (unsigned short)(u >> 16);
}

__device__ inline bf16x8 pack8(f32x4 lo, f32x4 hi) {
  bf16x8 r;
  r[0] = (short)f2bf(lo[0]); r[1] = (short)f2bf(lo[1]);
  r[2] = (short)f2bf(lo[2]); r[3] = (short)f2bf(lo[3]);
  r[4] = (short)f2bf(hi[0]); r[5] = (short)f2bf(hi[1]);
  r[6] = (short)f2bf(hi[2]); r[7] = (short)f2bf(hi[3]);
  return r;
}

// prep: X (768 blks) / Wr (48) / W1-split (32) -> bf16; zero cvec (1 blk)
__global__ __launch_bounds__(256) void prep_kernel(
    const float* __restrict__ X, const float* __restrict__ Wr,
    const float* __restrict__ W1,
    unsigned short* __restrict__ Xbf, unsigned short* __restrict__ Wrbf,
    unsigned short* __restrict__ W1bf, float* __restrict__ cvec) {
  int bid = blockIdx.x, tid = threadIdx.x;
  if (bid < 768) {
    size_t o = (size_t)bid * 2048 + tid * 8;
    *(bf16x8*)(Xbf + o) = pack8(*(const f32x4*)(X + o), *(const f32x4*)(X + o + 4));
  } else if (bid < 816) {
    size_t o = (size_t)(bid - 768) * 2048 + tid * 8;
    *(bf16x8*)(Wrbf + o) = pack8(*(const f32x4*)(Wr + o), *(const f32x4*)(Wr + o + 4));
  } else if (bid < 848) {
    size_t o = (size_t)(bid - 816) * 2048 + tid * 8;
    int m = (int)(o >> 7), k = (int)(o & 127);
    const float* src = (m < 256) ? (W1 + (size_t)m * 256 + k)
                                 : (W1 + (size_t)(m - 256) * 256 + 128 + k);
    *(bf16x8*)(W1bf + o) = pack8(*(const f32x4*)src, *(const f32x4*)(src + 4));
  } else {
    f32x4 z = {0.f, 0.f, 0.f, 0.f};
#pragma unroll
    for (int i = 0; i < 4; ++i)
      *(f32x4*)(cvec + tid * 16 + i * 4) = z;  // 256*16 = 4096 floats
  }
}

// GEMM1: e[2048][128] = X @ Wr^T + br (bf16 out). One 16x16 tile per wave,
// direct bf16 global loads (L2-resident), no LDS. 256 blocks (R5-proven).
__global__ __launch_bounds__(256) void gemm1_kernel(
    const unsigned short* __restrict__ Xbf, const unsigned short* __restrict__ Wrbf,
    const float* __restrict__ br, unsigned short* __restrict__ Ebf) {
  int wave = threadIdx.x >> 6, lane = threadIdx.x & 63;
  int tok0 = (blockIdx.x * 4 + wave) * 16;
  int n0 = blockIdx.y * 16;
  int lr = lane & 15, kg = (lane >> 4) * 8;
  const unsigned short* ap = Xbf + (size_t)(tok0 + lr) * 768 + kg;
  const unsigned short* bp = Wrbf + (size_t)(n0 + lr) * 768 + kg;
  f32x4 acc = {0, 0, 0, 0};
#pragma unroll 6
  for (int k0 = 0; k0 < 768; k0 += 32) {
    bf16x8 a = *(const bf16x8*)(ap + k0);
    bf16x8 b = *(const bf16x8*)(bp + k0);
    acc = __builtin_amdgcn_mfma_f32_16x16x32_bf16(a, b, acc, 0, 0, 0);
  }
  int rb = (lane >> 4) * 4;
  float bias = br[n0 + lr];
#pragma unroll
  for (int r = 0; r < 4; ++r)
    Ebf[(size_t)(tok0 + rb + r) * 128 + n0 + lr] = f2bf(acc[r] + bias);
}

// GEMM2 + fused cvec: UVt[512][2048] (0..255 = e@W1r^T + b1, 256..511 = e@W1c^T)
// bf16 W1bf (prep-converted); cvec via shfl-reduce + atomicAdd(0.5*p).
__global__ __launch_bounds__(256) void gemm2_kernel(
    const unsigned short* __restrict__ Ebf, const unsigned short* __restrict__ W1bf,
    const float* __restrict__ b1, const float* __restrict__ W2,
    float* __restrict__ UVt, float* __restrict__ cvec) {
  int wave = threadIdx.x >> 6, lane = threadIdx.x & 63;
  int t0 = blockIdx.x * 64;
  int m0 = (blockIdx.y * 4 + wave) * 16;
  int lr = lane & 15, kg = (lane >> 4) * 8;
  const unsigned short* aB = W1bf + (size_t)(m0 + lr) * 128 + kg;
  f32x4 acc[4] = {{0,0,0,0},{0,0,0,0},{0,0,0,0},{0,0,0,0}};
#pragma unroll
  for (int k0 = 0; k0 < 128; k0 += 32) {
    bf16x8 a = *(const bf16x8*)(aB + k0);
#pragma unroll
    for (int t = 0; t < 4; ++t) {
      bf16x8 b = *(const bf16x8*)(Ebf + (size_t)(t0 + t * 16 + lr) * 128 + kg + k0);
      acc[t] = __builtin_amdgcn_mfma_f32_16x16x32_bf16(a, b, acc[t], 0, 0, 0);
    }
  }
  int rb = (lane >> 4) * 4;
  float p[4] = {0.f, 0.f, 0.f, 0.f};
#pragma unroll
  for (int t = 0; t < 4; ++t) {
#pragma unroll
    for (int r = 0; r < 4; ++r) {
      int m = m0 + rb + r;
      float val = acc[t][r] + ((m0 < 256) ? b1[m] : 0.f);
      UVt[(size_t)m * 2048 + t0 + t * 16 + lr] = val;
      p[t] = fmaf(W2[m & 255], val, p[t]);
    }
  }
#pragma unroll
  for (int t = 0; t < 4; ++t) {
    p[t] += __shfl_xor(p[t], 16);
    p[t] += __shfl_xor(p[t], 32);
  }
  if (lane < 16) {
    int h = (m0 < 256) ? 0 : 1;
#pragma unroll
    for (int t = 0; t < 4; ++t)
      atomicAdd(&cvec[h * 2048 + t0 + t * 16 + lane], 0.5f * p[t]);
  }
}

// Pairwise: 32x32 tile/block, 4 waves m-split. NEW: two 32-m chunks per wave
// (wave-private LDS slices, no main-loop barriers) with register prefetch of
// chunk 1 during chunk 0 compute; 38KB LDS -> 4 blocks/CU (4 waves/SIMD).
__global__ __launch_bounds__(256, 4) void pairwise_kernel(
    const float* __restrict__ UVt, const float* __restrict__ W2,
    const float* __restrict__ cvec, const float* __restrict__ b2p,
    float* __restrict__ Out) {
  __shared__ float u_s[4][32][36];   // [wave][m-local][tok]  18KB
  __shared__ float v_s[4][32][36];   // 18KB
  __shared__ float w2_s[256];
  __shared__ float cuv[64];

  int tid = threadIdx.x;
  int wave = tid >> 6, lane = tid & 63;
  int b = blockIdx.y;
  int p = blockIdx.x;
  int it = 0;
  while (p >= 32 - it) { p -= 32 - it; ++it; }
  int jt = it + p;

  int utok = b * 1024 + it * 32;
  int vtok = b * 1024 + jt * 32;

  w2_s[tid] = W2[tid];
  if (tid < 32) cuv[tid] = cvec[utok + tid];
  else if (tid < 64) cuv[tid] = cvec[2048 + vtok + (tid - 32)];
  __syncthreads();  // w2_s/cuv visible; everything below is wave-private

  int mr = lane >> 3, tq = (lane & 7) * 4;
  int tx = lane & 7, ty = lane >> 3;
  int mb = wave * 64;
  float acc[4][4] = {{0,0,0,0},{0,0,0,0},{0,0,0,0},{0,0,0,0}};

  // prefetch chunk 0
  f32x4 pu[4], pv[4];
#pragma unroll
  for (int g = 0; g < 4; ++g) {
    int ml = g * 8 + mr;
    pu[g] = *(const f32x4*)(UVt + (size_t)(mb + ml) * 2048 + utok + tq);
    pv[g] = *(const f32x4*)(UVt + (size_t)(256 + mb + ml) * 2048 + vtok + tq);
  }

  for (int c = 0; c < 2; ++c) {
    // write prefetched chunk to this wave's LDS slice (in-order DS per wave)
#pragma unroll
    for (int g = 0; g < 4; ++g) {
      int ml = g * 8 + mr;
      *(f32x4*)&u_s[wave][ml][tq] = pu[g];
      *(f32x4*)&v_s[wave][ml][tq] = pv[g];
    }
    if (c == 0) {  // prefetch chunk 1 under chunk-0 compute
#pragma unroll
      for (int g = 0; g < 4; ++g) {
        int ml = g * 8 + mr;
        pu[g] = *(const f32x4*)(UVt + (size_t)(mb + 32 + ml) * 2048 + utok + tq);
        pv[g] = *(const f32x4*)(UVt + (size_t)(256 + mb + 32 + ml) * 2048 + vtok + tq);
      }
    }
    for (int ml = 0; ml < 32; ml += 4) {
      f32x4 wq = *(const f32x4*)&w2_s[mb + c * 32 + ml];
#pragma unroll
      for (int s = 0; s < 4; ++s) {
        f32x4 uu = *(const f32x4*)&u_s[wave][ml + s][4 * ty];
        f32x4 vv = *(const f32x4*)&v_s[wave][ml + s][4 * tx];
        float w = wq[s];
#pragma unroll
        for (int i = 0; i < 4; ++i)
#pragma unroll
          for (int j = 0; j < 4; ++j)
            acc[i][j] = fmaf(w, fabsf(uu[i] + vv[j]), acc[i][j]);
      }
    }
  }

  // all-wave combine via LDS overlays (R11-proven epilogue)
  float* ovp = (float*)u_s;   // [4][32][36] partials
  float* t2p = (float*)v_s;   // [32][36] transposed tile
  __syncthreads();            // all main-loop reads done before overlay writes
#pragma unroll
  for (int i = 0; i < 4; ++i) {
    f32x4 rv = {acc[i][0], acc[i][1], acc[i][2], acc[i][3]};
    *(f32x4*)&ovp[((size_t)wave * 32 + 4 * ty + i) * 36 + 4 * tx] = rv;
  }
  __syncthreads();

  int tc = lane & 7;
  int row = wave * 8 + (lane >> 3);
  float b2v = b2p[0];
  f32x4 sum = {0, 0, 0, 0};
#pragma unroll
  for (int q = 0; q < 4; ++q) {
    f32x4 part = *(const f32x4*)&ovp[((size_t)q * 32 + row) * 36 + 4 * tc];
#pragma unroll
    for (int j = 0; j < 4; ++j) sum[j] += part[j];
  }
  float cu = cuv[row];
  f32x4 val;
#pragma unroll
  for (int j = 0; j < 4; ++j)
    val[j] = 0.5f * sum[j] + cu + cuv[32 + 4 * tc + j] + b2v;

  *(f32x4*)&t2p[(size_t)row * 36 + 4 * tc] = val;

  size_t obase = (size_t)b << 20;
  int i0 = it * 32, j0 = jt * 32;
  if (it != jt)
    *(f32x4*)(Out + obase + (size_t)(i0 + row) * 1024 + j0 + 4 * tc) = val;
  else {
#pragma unroll
    for (int j = 0; j < 4; ++j) {
      int jl = 4 * tc + j;
      if (jl >= row) Out[obase + (size_t)(i0 + row) * 1024 + j0 + jl] = val[j];
    }
  }
  __syncthreads();  // t2p complete
  f32x4 mv;
#pragma unroll
  for (int j = 0; j < 4; ++j) mv[j] = t2p[(size_t)(4 * tc + j) * 36 + row];
  if (it != jt)
    *(f32x4*)(Out + obase + (size_t)(j0 + row) * 1024 + i0 + 4 * tc) = mv;
  else {
#pragma unroll
    for (int j = 0; j < 4; ++j) {
      int c = 4 * tc + j;
      if (row > c) Out[obase + (size_t)(i0 + row) * 1024 + j0 + c] = mv[j];
    }
  }
}

extern "C" void kernel_launch(void* const* d_in, const int* in_sizes, int n_in,
                              void* d_out, int out_size, void* d_ws, size_t ws_size,
                              hipStream_t stream) {
  (void)in_sizes; (void)n_in; (void)out_size; (void)ws_size;
  const float* X  = (const float*)d_in[0];
  const float* Wr = (const float*)d_in[1];
  const float* br = (const float*)d_in[2];
  const float* W1 = (const float*)d_in[3];
  const float* b1 = (const float*)d_in[4];
  const float* W2 = (const float*)d_in[5];
  const float* b2 = (const float*)d_in[6];
  float* Out = (float*)d_out;

  char* ws = (char*)d_ws;
  unsigned short* Xbf  = (unsigned short*)(ws);            // 3,145,728 B
  unsigned short* Wrbf = (unsigned short*)(ws + 3145728);  //   196,608 B
  unsigned short* W1bf = (unsigned short*)(ws + 3342336);  //   131,072 B
  unsigned short* Ebf  = (unsigned short*)(ws + 3473408);  //   524,288 B
  float*          UVt  = (float*)(ws + 3997696);           // 4,194,304 B
  float*          cvec = (float*)(ws + 8192000);           //    16,384 B

  prep_kernel<<<849, 256, 0, stream>>>(X, Wr, W1, Xbf, Wrbf, W1bf, cvec);
  gemm1_kernel<<<dim3(32, 8), 256, 0, stream>>>(Xbf, Wrbf, br, Ebf);
  gemm2_kernel<<<dim3(32, 8), 256, 0, stream>>>(Ebf, W1bf, b1, W2, UVt, cvec);
  pairwise_kernel<<<dim3(528, 2), 256, 0, stream>>>(UVt, W2, cvec, b2, Out);
}

// Round 14
// 69.947 us; speedup vs baseline: 1.9306x; 1.3275x over previous
//
#include <hip/hip_runtime.h>

typedef __attribute__((ext_vector_type(4))) float f32x4;
typedef __attribute__((ext_vector_type(8))) short bf16x8;

// f32 -> bf16 round-to-nearest-even
__device__ inline unsigned short f2bf(float x) {
  unsigned u = __builtin_bit_cast(unsigned, x);
  u += 0x7fffu + ((u >> 16) & 1u);
  return (unsigned short)(u >> 16);
}

__device__ inline bf16x8 pack8(f32x4 lo, f32x4 hi) {
  bf16x8 r;
  r[0] = (short)f2bf(lo[0]); r[1] = (short)f2bf(lo[1]);
  r[2] = (short)f2bf(lo[2]); r[3] = (short)f2bf(lo[3]);
  r[4] = (short)f2bf(hi[0]); r[5] = (short)f2bf(hi[1]);
  r[6] = (short)f2bf(hi[2]); r[7] = (short)f2bf(hi[3]);
  return r;
}

__device__ inline float bf2f(short s) {
  return __builtin_bit_cast(float, ((unsigned)(unsigned short)s) << 16);
}

// prep: X (768 blks) / Wr (48) / W1-split (32) -> bf16; zero cvec (1 blk)
__global__ __launch_bounds__(256) void prep_kernel(
    const float* __restrict__ X, const float* __restrict__ Wr,
    const float* __restrict__ W1,
    unsigned short* __restrict__ Xbf, unsigned short* __restrict__ Wrbf,
    unsigned short* __restrict__ W1bf, float* __restrict__ cvec) {
  int bid = blockIdx.x, tid = threadIdx.x;
  if (bid < 768) {
    size_t o = (size_t)bid * 2048 + tid * 8;
    *(bf16x8*)(Xbf + o) = pack8(*(const f32x4*)(X + o), *(const f32x4*)(X + o + 4));
  } else if (bid < 816) {
    size_t o = (size_t)(bid - 768) * 2048 + tid * 8;
    *(bf16x8*)(Wrbf + o) = pack8(*(const f32x4*)(Wr + o), *(const f32x4*)(Wr + o + 4));
  } else if (bid < 848) {
    size_t o = (size_t)(bid - 816) * 2048 + tid * 8;
    int m = (int)(o >> 7), k = (int)(o & 127);
    const float* src = (m < 256) ? (W1 + (size_t)m * 256 + k)
                                 : (W1 + (size_t)(m - 256) * 256 + 128 + k);
    *(bf16x8*)(W1bf + o) = pack8(*(const f32x4*)src, *(const f32x4*)(src + 4));
  } else {
    f32x4 z = {0.f, 0.f, 0.f, 0.f};
#pragma unroll
    for (int i = 0; i < 4; ++i)
      *(f32x4*)(cvec + tid * 16 + i * 4) = z;  // 256*16 = 4096 floats
  }
}

// GEMM1: e[2048][128] = X @ Wr^T + br (bf16 out). One 16x16 tile per wave,
// direct bf16 global loads (L2-resident), no LDS. 256 blocks (R5-proven).
__global__ __launch_bounds__(256) void gemm1_kernel(
    const unsigned short* __restrict__ Xbf, const unsigned short* __restrict__ Wrbf,
    const float* __restrict__ br, unsigned short* __restrict__ Ebf) {
  int wave = threadIdx.x >> 6, lane = threadIdx.x & 63;
  int tok0 = (blockIdx.x * 4 + wave) * 16;
  int n0 = blockIdx.y * 16;
  int lr = lane & 15, kg = (lane >> 4) * 8;
  const unsigned short* ap = Xbf + (size_t)(tok0 + lr) * 768 + kg;
  const unsigned short* bp = Wrbf + (size_t)(n0 + lr) * 768 + kg;
  f32x4 acc = {0, 0, 0, 0};
#pragma unroll 6
  for (int k0 = 0; k0 < 768; k0 += 32) {
    bf16x8 a = *(const bf16x8*)(ap + k0);
    bf16x8 b = *(const bf16x8*)(bp + k0);
    acc = __builtin_amdgcn_mfma_f32_16x16x32_bf16(a, b, acc, 0, 0, 0);
  }
  int rb = (lane >> 4) * 4;
  float bias = br[n0 + lr];
#pragma unroll
  for (int r = 0; r < 4; ++r)
    Ebf[(size_t)(tok0 + rb + r) * 128 + n0 + lr] = f2bf(acc[r] + bias);
}

// GEMM2 + fused cvec: UVbf[512][2048] bf16 (0..255 = e@W1r^T + b1, 256..511 =
// e@W1c^T); cvec via shfl-reduce + atomicAdd(0.5*p) on f32 values.
__global__ __launch_bounds__(256) void gemm2_kernel(
    const unsigned short* __restrict__ Ebf, const unsigned short* __restrict__ W1bf,
    const float* __restrict__ b1, const float* __restrict__ W2,
    unsigned short* __restrict__ UVbf, float* __restrict__ cvec) {
  int wave = threadIdx.x >> 6, lane = threadIdx.x & 63;
  int t0 = blockIdx.x * 64;
  int m0 = (blockIdx.y * 4 + wave) * 16;
  int lr = lane & 15, kg = (lane >> 4) * 8;
  const unsigned short* aB = W1bf + (size_t)(m0 + lr) * 128 + kg;
  f32x4 acc[4] = {{0,0,0,0},{0,0,0,0},{0,0,0,0},{0,0,0,0}};
#pragma unroll
  for (int k0 = 0; k0 < 128; k0 += 32) {
    bf16x8 a = *(const bf16x8*)(aB + k0);
#pragma unroll
    for (int t = 0; t < 4; ++t) {
      bf16x8 b = *(const bf16x8*)(Ebf + (size_t)(t0 + t * 16 + lr) * 128 + kg + k0);
      acc[t] = __builtin_amdgcn_mfma_f32_16x16x32_bf16(a, b, acc[t], 0, 0, 0);
    }
  }
  int rb = (lane >> 4) * 4;
  float p[4] = {0.f, 0.f, 0.f, 0.f};
#pragma unroll
  for (int t = 0; t < 4; ++t) {
#pragma unroll
    for (int r = 0; r < 4; ++r) {
      int m = m0 + rb + r;
      float val = acc[t][r] + ((m0 < 256) ? b1[m] : 0.f);
      UVbf[(size_t)m * 2048 + t0 + t * 16 + lr] = f2bf(val);
      p[t] = fmaf(W2[m & 255], val, p[t]);
    }
  }
#pragma unroll
  for (int t = 0; t < 4; ++t) {
    p[t] += __shfl_xor(p[t], 16);
    p[t] += __shfl_xor(p[t], 32);
  }
  if (lane < 16) {
    int h = (m0 < 256) ? 0 : 1;
#pragma unroll
    for (int t = 0; t < 4; ++t)
      atomicAdd(&cvec[h * 2048 + t0 + t * 16 + lane], 0.5f * p[t]);
  }
}

// Pairwise: 32x32 tile/block, 4 waves m-split, two 32-m chunks with register
// prefetch (R13 structure). NEW: bf16 UV loads (16B/lane) + XCD-aware task
// swizzle so each XCD's 1MB batch slice stays L2-resident.
__global__ __launch_bounds__(256, 4) void pairwise_kernel(
    const unsigned short* __restrict__ UVbf, const float* __restrict__ W2,
    const float* __restrict__ cvec, const float* __restrict__ b2p,
    float* __restrict__ Out) {
  __shared__ float u_s[4][32][36];   // [wave][m-local][tok]
  __shared__ float v_s[4][32][36];
  __shared__ float w2_s[256];
  __shared__ float cuv[64];

  int tid = threadIdx.x;
  int wave = tid >> 6, lane = tid & 63;
  // XCD swizzle: 1056 tasks, XCD k owns tasks [k*132, (k+1)*132)
  int bid = blockIdx.x;
  int task = (bid & 7) * 132 + (bid >> 3);
  int b = task >= 528 ? 1 : 0;
  int p = task - b * 528;
  int it = 0;
  while (p >= 32 - it) { p -= 32 - it; ++it; }
  int jt = it + p;

  int utok = b * 1024 + it * 32;
  int vtok = b * 1024 + jt * 32;

  w2_s[tid] = W2[tid];
  if (tid < 32) cuv[tid] = cvec[utok + tid];
  else if (tid < 64) cuv[tid] = cvec[2048 + vtok + (tid - 32)];
  __syncthreads();  // w2_s/cuv visible; everything below is wave-private

  int mr = lane >> 2;            // 0..15 (row within 16-row pass)
  int tq = (lane & 3) * 8;       // 0,8,16,24 (8-tok group, 16B loads)
  int tx = lane & 7, ty = lane >> 3;
  int mb = wave * 64;
  float acc[4][4] = {{0,0,0,0},{0,0,0,0},{0,0,0,0},{0,0,0,0}};

  // prefetch chunk 0 (bf16, 16B per lane per row-pass)
  bf16x8 pu[2], pv[2];
#pragma unroll
  for (int g = 0; g < 2; ++g) {
    int ml = g * 16 + mr;
    pu[g] = *(const bf16x8*)(UVbf + (size_t)(mb + ml) * 2048 + utok + tq);
    pv[g] = *(const bf16x8*)(UVbf + (size_t)(256 + mb + ml) * 2048 + vtok + tq);
  }

  for (int c = 0; c < 2; ++c) {
    // write prefetched chunk to this wave's LDS slice (cvt bf16->f32)
#pragma unroll
    for (int g = 0; g < 2; ++g) {
      int ml = g * 16 + mr;
      f32x4 lo, hi, lov, hiv;
#pragma unroll
      for (int k = 0; k < 4; ++k) {
        lo[k] = bf2f(pu[g][k]); hi[k] = bf2f(pu[g][4 + k]);
        lov[k] = bf2f(pv[g][k]); hiv[k] = bf2f(pv[g][4 + k]);
      }
      *(f32x4*)&u_s[wave][ml][tq] = lo;
      *(f32x4*)&u_s[wave][ml][tq + 4] = hi;
      *(f32x4*)&v_s[wave][ml][tq] = lov;
      *(f32x4*)&v_s[wave][ml][tq + 4] = hiv;
    }
    if (c == 0) {  // prefetch chunk 1 under chunk-0 compute
#pragma unroll
      for (int g = 0; g < 2; ++g) {
        int ml = g * 16 + mr;
        pu[g] = *(const bf16x8*)(UVbf + (size_t)(mb + 32 + ml) * 2048 + utok + tq);
        pv[g] = *(const bf16x8*)(UVbf + (size_t)(256 + mb + 32 + ml) * 2048 + vtok + tq);
      }
    }
    for (int ml = 0; ml < 32; ml += 4) {
      f32x4 wq = *(const f32x4*)&w2_s[mb + c * 32 + ml];
#pragma unroll
      for (int s = 0; s < 4; ++s) {
        f32x4 uu = *(const f32x4*)&u_s[wave][ml + s][4 * ty];
        f32x4 vv = *(const f32x4*)&v_s[wave][ml + s][4 * tx];
        float w = wq[s];
#pragma unroll
        for (int i = 0; i < 4; ++i)
#pragma unroll
          for (int j = 0; j < 4; ++j)
            acc[i][j] = fmaf(w, fabsf(uu[i] + vv[j]), acc[i][j]);
      }
    }
  }

  // all-wave combine via LDS overlays (R11-proven epilogue)
  float* ovp = (float*)u_s;   // [4][32][36] partials
  float* t2p = (float*)v_s;   // [32][36] transposed tile
  __syncthreads();            // all main-loop reads done before overlay writes
#pragma unroll
  for (int i = 0; i < 4; ++i) {
    f32x4 rv = {acc[i][0], acc[i][1], acc[i][2], acc[i][3]};
    *(f32x4*)&ovp[((size_t)wave * 32 + 4 * ty + i) * 36 + 4 * tx] = rv;
  }
  __syncthreads();

  int tc = lane & 7;
  int row = wave * 8 + (lane >> 3);
  float b2v = b2p[0];
  f32x4 sum = {0, 0, 0, 0};
#pragma unroll
  for (int q = 0; q < 4; ++q) {
    f32x4 part = *(const f32x4*)&ovp[((size_t)q * 32 + row) * 36 + 4 * tc];
#pragma unroll
    for (int j = 0; j < 4; ++j) sum[j] += part[j];
  }
  float cu = cuv[row];
  f32x4 val;
#pragma unroll
  for (int j = 0; j < 4; ++j)
    val[j] = 0.5f * sum[j] + cu + cuv[32 + 4 * tc + j] + b2v;

  *(f32x4*)&t2p[(size_t)row * 36 + 4 * tc] = val;

  size_t obase = (size_t)b << 20;
  int i0 = it * 32, j0 = jt * 32;
  if (it != jt)
    *(f32x4*)(Out + obase + (size_t)(i0 + row) * 1024 + j0 + 4 * tc) = val;
  else {
#pragma unroll
    for (int j = 0; j < 4; ++j) {
      int jl = 4 * tc + j;
      if (jl >= row) Out[obase + (size_t)(i0 + row) * 1024 + j0 + jl] = val[j];
    }
  }
  __syncthreads();  // t2p complete
  f32x4 mv;
#pragma unroll
  for (int j = 0; j < 4; ++j) mv[j] = t2p[(size_t)(4 * tc + j) * 36 + row];
  if (it != jt)
    *(f32x4*)(Out + obase + (size_t)(j0 + row) * 1024 + i0 + 4 * tc) = mv;
  else {
#pragma unroll
    for (int j = 0; j < 4; ++j) {
      int c = 4 * tc + j;
      if (row > c) Out[obase + (size_t)(i0 + row) * 1024 + j0 + c] = mv[j];
    }
  }
}

extern "C" void kernel_launch(void* const* d_in, const int* in_sizes, int n_in,
                              void* d_out, int out_size, void* d_ws, size_t ws_size,
                              hipStream_t stream) {
  (void)in_sizes; (void)n_in; (void)out_size; (void)ws_size;
  const float* X  = (const float*)d_in[0];
  const float* Wr = (const float*)d_in[1];
  const float* br = (const float*)d_in[2];
  const float* W1 = (const float*)d_in[3];
  const float* b1 = (const float*)d_in[4];
  const float* W2 = (const float*)d_in[5];
  const float* b2 = (const float*)d_in[6];
  float* Out = (float*)d_out;

  char* ws = (char*)d_ws;
  unsigned short* Xbf  = (unsigned short*)(ws);            // 3,145,728 B
  unsigned short* Wrbf = (unsigned short*)(ws + 3145728);  //   196,608 B
  unsigned short* W1bf = (unsigned short*)(ws + 3342336);  //   131,072 B
  unsigned short* Ebf  = (unsigned short*)(ws + 3473408);  //   524,288 B
  unsigned short* UVbf = (unsigned short*)(ws + 3997696);  // 2,097,152 B
  float*          cvec = (float*)(ws + 6094848);           //    16,384 B

  prep_kernel<<<849, 256, 0, stream>>>(X, Wr, W1, Xbf, Wrbf, W1bf, cvec);
  gemm1_kernel<<<dim3(32, 8), 256, 0, stream>>>(Xbf, Wrbf, br, Ebf);
  gemm2_kernel<<<dim3(32, 8), 256, 0, stream>>>(Ebf, W1bf, b1, W2, UVbf, cvec);
  pairwise_kernel<<<1056, 256, 0, stream>>>(UVbf, W2, cvec, b2, Out);
}